// Round 19
// baseline (278.636 us; speedup 1.0000x reference)
//
#include <hip/hip_runtime.h>
#include <stdint.h>

typedef short bf16x4 __attribute__((ext_vector_type(4)));
typedef short bf16x8 __attribute__((ext_vector_type(8)));
typedef _Float16 f16x8 __attribute__((ext_vector_type(8)));
typedef float f32x4 __attribute__((ext_vector_type(4)));
typedef float f32x16 __attribute__((ext_vector_type(16)));
typedef unsigned int u32x4 __attribute__((ext_vector_type(4)));
typedef unsigned int u32x2 __attribute__((ext_vector_type(2)));

#if __has_builtin(__builtin_amdgcn_exp2f)
#define EXP2 __builtin_amdgcn_exp2f
#else
#define EXP2 exp2f
#endif

// ---------- helpers ----------
__device__ __forceinline__ short f2bf(float f) {  // RNE f32->bf16 (finite inputs)
  union { float f; uint32_t u; } v; v.f = f;
  uint32_t r = (v.u + 0x7fffu + ((v.u >> 16) & 1u)) >> 16;
  return (short)(uint16_t)r;
}

__device__ __forceinline__ unsigned cvtpk_bf16(float lo, float hi) {
  unsigned r;
  asm("v_cvt_pk_bf16_f32 %0, %1, %2" : "=v"(r) : "v"(lo), "v"(hi));
  return r;
}

// v_permlane32_swap_b32 via the BUILTIN (hazard-safe; round-5 verified).
#if __has_builtin(__builtin_amdgcn_permlane32_swap)
__device__ __forceinline__ void plane32_swap(unsigned& a, unsigned& b) {
  u32x2 r = __builtin_amdgcn_permlane32_swap(a, b, false, false);
  a = r[0]; b = r[1];
}
#else
__device__ __forceinline__ void plane32_swap(unsigned& a, unsigned& b) {
  asm("s_nop 1\n\tv_permlane32_swap_b32 %0, %1" : "+v"(a), "+v"(b));
}
#endif

__device__ __forceinline__ f32x16 zero16() {
  f32x16 z;
#pragma unroll
  for (int i = 0; i < 16; ++i) z[i] = 0.f;
  return z;
}

__device__ __forceinline__ void gld_lds16(const void* g, void* l) {
  __builtin_amdgcn_global_load_lds(
      (__attribute__((address_space(1))) const void*)g,
      (__attribute__((address_space(3))) void*)l, 16, 0, 0);
}

// ---------- RMSNorm + cast to bf16 ----------
__global__ __launch_bounds__(256) void k_rmsnorm(const float* __restrict__ x,
                                                 const float* __restrict__ wn,
                                                 short* __restrict__ xn) {
  const int row = blockIdx.x;      // 8192 rows
  const int t = threadIdx.x;       // 256 threads, 4 floats each
  const float4 v = reinterpret_cast<const float4*>(x + (size_t)row * 1024)[t];
  float ss = v.x * v.x + v.y * v.y + v.z * v.z + v.w * v.w;
#pragma unroll
  for (int m = 32; m >= 1; m >>= 1) ss += __shfl_xor(ss, m, 64);
  __shared__ float red[4];
  if ((t & 63) == 0) red[t >> 6] = ss;
  __syncthreads();
  const float tot = red[0] + red[1] + red[2] + red[3];
  const float rr = rsqrtf(tot * (1.0f / 1024.0f) + 1e-5f);
  const float4 g = reinterpret_cast<const float4*>(wn)[t];
  bf16x4 o;
  o[0] = f2bf(v.x * rr * g.x);
  o[1] = f2bf(v.y * rr * g.y);
  o[2] = f2bf(v.z * rr * g.z);
  o[3] = f2bf(v.w * rr * g.w);
  reinterpret_cast<bf16x4*>(xn + (size_t)row * 1024)[t] = o;
}

// ---------- casts ----------
__global__ __launch_bounds__(256) void k_cast_bf(const float* __restrict__ in,
                                                 short* __restrict__ out, int n4) {
  int i = blockIdx.x * 256 + threadIdx.x;
  if (i >= n4) return;
  float4 v = reinterpret_cast<const float4*>(in)[i];
  bf16x4 o;
  o[0] = f2bf(v.x); o[1] = f2bf(v.y); o[2] = f2bf(v.z); o[3] = f2bf(v.w);
  reinterpret_cast<bf16x4*>(out)[i] = o;
}

__global__ __launch_bounds__(256) void k_cast_f16(const float* __restrict__ in,
                                                  _Float16* __restrict__ out, int n4) {
  int i = blockIdx.x * 256 + threadIdx.x;
  if (i >= n4) return;
  float4 v = reinterpret_cast<const float4*>(in)[i];
  _Float16 o[4] = {(_Float16)v.x, (_Float16)v.y, (_Float16)v.z, (_Float16)v.w};
  reinterpret_cast<ulong1*>(out)[i] = *reinterpret_cast<ulong1*>(o);
}

// ---------- QKV GEMM v4: BK=64 + 2-deep double-buffer, counted vmcnt ----------
// Round-18 residual: per-K-step full vmcnt(0) drain (inside __syncthreads)
// exposed HBM/L2 latency 16x per block. v4 uses the attn-v13-proven scheme:
// prologue stages tiles 0,1; per iter vmcnt(8)+barrier (tile kt landed, kt+1
// in flight ~1.5 iters ahead), read ks0 -> MFMA ks0 -> read ks1 -> lgkmcnt(0)
// -> barrier2 (ALL waves' reads of this buffer drained) -> stage tile kt+2
// into the just-read buffer -> MFMA ks1. Tail stages clamp to tile 15 (junk,
// post-drain, never read). XOR swizzle (both sides) retained from v3.
__global__ __launch_bounds__(256) void k_gemm_qkv(const short* __restrict__ A,
                                                  const short* __restrict__ B,
                                                  const float* __restrict__ bias,
                                                  short* __restrict__ qb,
                                                  short* __restrict__ kfrag,
                                                  short* __restrict__ vfrag) {
  __shared__ __align__(16) short As[2][8192];  // 2 x 16KB
  __shared__ __align__(16) short Bs[2][8192];  // 2 x 16KB
  const int t = threadIdx.x;
  // T1: XCD-aware remap (nwg = 24*64 = 1536, 1536%8==0)
  const int orig = blockIdx.y * 24 + blockIdx.x;
  const int swz = (orig & 7) * 192 + (orig >> 3);
  const long bn0 = (long)(swz % 24) * 128;
  const long bm0 = (long)(swz / 24) * 128;
  const int w = t >> 6, l = t & 63;
  const int wr = (w >> 1) * 64, wc = (w & 1) * 64;
  const int lm = l & 15, h = l >> 4;
  f32x4 acc[4][4];
#pragma unroll
  for (int i = 0; i < 4; ++i)
#pragma unroll
    for (int j = 0; j < 4; ++j) acc[i][j] = (f32x4){0.f, 0.f, 0.f, 0.f};
  int ssrc[4], sdst[4];
#pragma unroll
  for (int i = 0; i < 4; ++i) {
    const int idx = i * 256 + t;
    const int row = idx >> 3, gc = idx & 7;
    ssrc[i] = row * 1024 + ((gc ^ (row & 7)) * 8);
    sdst[i] = idx * 8;
  }
  const short* Ag = A + bm0 * 1024;
  const short* Bg = B + bn0 * 1024;
  int aoff[4][2], boff[4][2];
#pragma unroll
  for (int mi = 0; mi < 4; ++mi) {
#pragma unroll
    for (int ks = 0; ks < 2; ++ks) {
      const int ra = wr + mi * 16 + lm;
      aoff[mi][ks] = ra * 64 + (((ks * 4 + h) ^ (ra & 7)) * 8);
      const int rb = wc + mi * 16 + lm;
      boff[mi][ks] = rb * 64 + (((ks * 4 + h) ^ (rb & 7)) * 8);
    }
  }
  auto STAGE = [&](int buf, int kt) {
    const int k0 = kt * 64;
#pragma unroll
    for (int i = 0; i < 4; ++i) gld_lds16(Ag + k0 + ssrc[i], &As[buf][sdst[i]]);
#pragma unroll
    for (int i = 0; i < 4; ++i) gld_lds16(Bg + k0 + ssrc[i], &Bs[buf][sdst[i]]);
  };
  // prologue: tiles 0 (buf0) and 1 (buf1): 16 loads in flight (8 per wave)
  STAGE(0, 0);
  STAGE(1, 1);

  for (int kt = 0; kt < 16; ++kt) {
    // this wave's tile-kt 8 loads retired; kt+1's 8 in flight. Barrier:
    // every wave passed its own vmcnt -> all of tile kt is in LDS.
    asm volatile("s_waitcnt vmcnt(8)" ::: "memory");
    __builtin_amdgcn_s_barrier();
    const int buf = kt & 1;
    // ksub 0
    bf16x8 af[4], bfr[4];
#pragma unroll
    for (int mi = 0; mi < 4; ++mi) af[mi] = *reinterpret_cast<const bf16x8*>(&As[buf][aoff[mi][0]]);
#pragma unroll
    for (int ni = 0; ni < 4; ++ni) bfr[ni] = *reinterpret_cast<const bf16x8*>(&Bs[buf][boff[ni][0]]);
    asm volatile("s_waitcnt lgkmcnt(0)" ::: "memory");
    __builtin_amdgcn_sched_barrier(0);
    __builtin_amdgcn_s_setprio(1);
#pragma unroll
    for (int mi = 0; mi < 4; ++mi)
#pragma unroll
      for (int ni = 0; ni < 4; ++ni)
        acc[mi][ni] = __builtin_amdgcn_mfma_f32_16x16x32_bf16(af[mi], bfr[ni], acc[mi][ni], 0, 0, 0);
    __builtin_amdgcn_s_setprio(0);
    // ksub 1 reads
#pragma unroll
    for (int mi = 0; mi < 4; ++mi) af[mi] = *reinterpret_cast<const bf16x8*>(&As[buf][aoff[mi][1]]);
#pragma unroll
    for (int ni = 0; ni < 4; ++ni) bfr[ni] = *reinterpret_cast<const bf16x8*>(&Bs[buf][boff[ni][1]]);
    asm volatile("s_waitcnt lgkmcnt(0)" ::: "memory");
    __builtin_amdgcn_sched_barrier(0);
    __builtin_amdgcn_s_barrier();  // ALL waves done reading buf -> overwrite ok
    int kn = kt + 2; if (kn > 15) kn = 15;  // tail: junk re-stage, never read
    STAGE(buf, kn);
    __builtin_amdgcn_s_setprio(1);
#pragma unroll
    for (int mi = 0; mi < 4; ++mi)
#pragma unroll
      for (int ni = 0; ni < 4; ++ni)
        acc[mi][ni] = __builtin_amdgcn_mfma_f32_16x16x32_bf16(af[mi], bfr[ni], acc[mi][ni], 0, 0, 0);
    __builtin_amdgcn_s_setprio(0);
  }
#pragma unroll
  for (int ni = 0; ni < 4; ++ni) {
    const int ncol = (int)bn0 + wc + ni * 16 + lm;
    const float bv = bias[ncol];
    const int which = ncol >> 10;
    const int e = ncol & 1023;
    const int hd = e >> 6, d = e & 63;
#pragma unroll
    for (int mi = 0; mi < 4; ++mi) {
#pragma unroll
      for (int r = 0; r < 4; ++r) {
        const long mrow = bm0 + wr + mi * 16 + h * 4 + r;
        const float val = acc[mi][ni][r] + bv;
        const long bh = (mrow >> 11) * 16 + hd;
        const int seq = (int)(mrow & 2047);
        if (which == 0) {
          const long off = (bh * 2048 + seq) * 64 + d;
          qb[off] = f2bf(val * 0.18033688011112042f);  // 0.125*log2(e)
        } else if (which == 1) {
          const long off = ((bh * 64 + (seq >> 5)) * 4 + (d >> 4)) * 512 +
                           ((seq & 31) | (((d >> 3) & 1) << 5)) * 8 + (d & 7);
          kfrag[off] = f2bf(val);
        } else {
          const long off = (((bh * 64 + (seq >> 5)) * 2 + (d >> 5)) * 2 +
                            ((seq >> 4) & 1)) * 512 +
                           ((d & 31) | (((seq >> 3) & 1) << 5)) * 8 + (seq & 7);
          vfrag[off] = f2bf(val);
        }
      }
    }
  }
}

// ---------- out-proj GEMM (fp16 inputs for precision, fp32 out) ----------
__global__ __launch_bounds__(256) void k_gemm_out(const _Float16* __restrict__ A,
                                                  const _Float16* __restrict__ B,
                                                  const float* __restrict__ bias,
                                                  float* __restrict__ outp) {
  __shared__ __align__(16) _Float16 As[128 * 32];
  __shared__ __align__(16) _Float16 Bs[128 * 32];
  const int t = threadIdx.x;
  // T1: nwg = 8*64 = 512, 512%8==0
  const int orig = blockIdx.y * 8 + blockIdx.x;
  const int swz = (orig & 7) * 64 + (orig >> 3);
  const long bn0 = (long)(swz % 8) * 128;
  const long bm0 = (long)(swz / 8) * 128;
  const int w = t >> 6, l = t & 63;
  const int wr = (w >> 1) * 64, wc = (w & 1) * 64;
  const int lm = l & 15, h = l >> 4;
  f32x4 acc[4][4];
#pragma unroll
  for (int i = 0; i < 4; ++i)
#pragma unroll
    for (int j = 0; j < 4; ++j) acc[i][j] = (f32x4){0.f, 0.f, 0.f, 0.f};
  const int srow = t >> 2, scol = (t & 3) * 8;
  const _Float16* Ag = A + (bm0 + srow) * 1024 + scol;
  const _Float16* Bg = B + (bn0 + srow) * 1024 + scol;
  _Float16* AsP = As + t * 8;
  _Float16* BsP = Bs + t * 8;
  for (int kt = 0; kt < 32; ++kt) {
    const int k0 = kt << 5;
    gld_lds16(Ag + k0, AsP);
    gld_lds16(Ag + k0 + 64 * 1024, AsP + 2048);
    gld_lds16(Bg + k0, BsP);
    gld_lds16(Bg + k0 + 64 * 1024, BsP + 2048);
    __syncthreads();
    f16x8 af[4], bfr[4];
#pragma unroll
    for (int mi = 0; mi < 4; ++mi)
      af[mi] = *reinterpret_cast<const f16x8*>(As + (wr + mi * 16 + lm) * 32 + h * 8);
#pragma unroll
    for (int ni = 0; ni < 4; ++ni)
      bfr[ni] = *reinterpret_cast<const f16x8*>(Bs + (wc + ni * 16 + lm) * 32 + h * 8);
    __builtin_amdgcn_s_setprio(1);
#pragma unroll
    for (int mi = 0; mi < 4; ++mi)
#pragma unroll
      for (int ni = 0; ni < 4; ++ni)
        acc[mi][ni] = __builtin_amdgcn_mfma_f32_16x16x32_f16(af[mi], bfr[ni], acc[mi][ni], 0, 0, 0);
    __builtin_amdgcn_s_setprio(0);
    __syncthreads();
  }
#pragma unroll
  for (int ni = 0; ni < 4; ++ni) {
    const int ncol = (int)bn0 + wc + ni * 16 + lm;
    const float bv = bias[ncol];
#pragma unroll
    for (int mi = 0; mi < 4; ++mi) {
#pragma unroll
      for (int r = 0; r < 4; ++r) {
        const long mrow = bm0 + wr + mi * 16 + h * 4 + r;
        outp[mrow * 1024 + ncol] = acc[mi][ni][r] + bv;
      }
    }
  }
}

// ---------- flash attention v15: v14 + shift folded into QK MFMA C-operand ----------
// s = mfma(kf0, qf0, M16) with persistent M16 = (-16.0)x16 seeds the QK
// accumulation at -16: deletes BOTH the per-iter 16x v_mov zero-init AND the
// 16x v_sub before exp2 (~32 of ~50 VALU ops/iter) at zero MFMA cost.
// Identical math (the -16 is added in the f32 MFMA accumulate).
__global__ __launch_bounds__(256, 4) void k_attn(const short* __restrict__ q,
                                                 const short* __restrict__ kfrag,
                                                 const short* __restrict__ vfrag,
                                                 _Float16* __restrict__ o) {
  __shared__ __align__(16) short KV[4][4096];  // per tile: K 2048 | V 2048 shorts
  const int orig = blockIdx.y * 16 + blockIdx.x;
  const int work = (orig & 7) * 128 + (orig >> 3);
  const int bh = work >> 4;    // 64 heads
  const int qt = work & 15;    // 16 q-tiles of 128 rows
  const int t = threadIdx.x;
  const int w = t >> 6, l = t & 63;
  const int lq = l & 31, hh = l >> 5;
  const int qrow = qt * 128 + w * 32 + lq;

  bf16x8 qf[4];
  const short* qp = q + ((size_t)(bh * 2048 + qrow)) * 64 + hh * 8;
#pragma unroll
  for (int db = 0; db < 4; ++db)
    qf[db] = *reinterpret_cast<const bf16x8*>(qp + db * 16);

  bf16x8 ones;
#pragma unroll
  for (int i = 0; i < 8; ++i) ones[i] = (short)0x3F80;  // bf16 1.0

  f32x16 m16c;  // persistent QK seed: softmax shift folded into MFMA C
#pragma unroll
  for (int i = 0; i < 16; ++i) m16c[i] = -16.f;

  const int goff = (w * 64 + l) * 8;  // shorts (lane-linear, wave-uniform base)
  const short* ksrc = kfrag + (size_t)bh * 64 * 2048 + goff;  // + kt*2048
  const short* vsrc = vfrag + (size_t)bh * 64 * 2048 + goff;

  f32x16 oa0 = zero16(), oa1 = zero16(), oaS = zero16();

#pragma unroll
  for (int p = 0; p < 3; ++p) {
    gld_lds16(ksrc + p * 2048, &KV[p][goff]);
    gld_lds16(vsrc + p * 2048, &KV[p][2048 + goff]);
  }

#pragma unroll 1
  for (int kt = 0; kt < 64; ++kt) {
    asm volatile("s_waitcnt vmcnt(4)" ::: "memory");
    __builtin_amdgcn_s_barrier();
    const short* kb_ = KV[kt & 3];
    bf16x8 kf[4], vf[4];
#pragma unroll
    for (int db = 0; db < 4; ++db)
      kf[db] = *reinterpret_cast<const bf16x8*>(kb_ + db * 512 + l * 8);
#pragma unroll
    for (int i = 0; i < 4; ++i)
      vf[i] = *reinterpret_cast<const bf16x8*>(kb_ + 2048 + i * 512 + l * 8);
    // stage tile kt+3 (its readers finished before barrier(kt); tail clamp)
    int kn = kt + 3; if (kn > 63) kn = 63;
    gld_lds16(ksrc + kn * 2048, &KV[(kt + 3) & 3][goff]);
    gld_lds16(vsrc + kn * 2048, &KV[(kt + 3) & 3][2048 + goff]);

    asm volatile("s_waitcnt lgkmcnt(4)" ::: "memory");  // K frags ready
    __builtin_amdgcn_sched_barrier(0);                  // rule #18 fence
    __builtin_amdgcn_s_setprio(1);
    f32x16 s = __builtin_amdgcn_mfma_f32_32x32x16_bf16(kf[0], qf[0], m16c, 0, 0, 0);
#pragma unroll
    for (int db = 1; db < 4; ++db)
      s = __builtin_amdgcn_mfma_f32_32x32x16_bf16(kf[db], qf[db], s, 0, 0, 0);
    __builtin_amdgcn_s_setprio(0);
    asm volatile("s_waitcnt lgkmcnt(0)" ::: "memory");  // V frags ready
    __builtin_amdgcn_sched_barrier(0);
    // shift softmax: p = exp2(QK - 16); shift already in s via m16c
#pragma unroll
    for (int r = 0; r < 16; ++r) s[r] = EXP2(s[r]);
    __builtin_amdgcn_s_setprio(1);
#pragma unroll
    for (int kg = 0; kg < 2; ++kg) {
      const int b0 = kg * 8;
      unsigned w0 = cvtpk_bf16(s[b0 + 0], s[b0 + 1]);
      unsigned w1 = cvtpk_bf16(s[b0 + 2], s[b0 + 3]);
      unsigned w2 = cvtpk_bf16(s[b0 + 4], s[b0 + 5]);
      unsigned w3 = cvtpk_bf16(s[b0 + 6], s[b0 + 7]);
      plane32_swap(w0, w2);
      plane32_swap(w1, w3);
      u32x4 pw = {w0, w1, w2, w3};
      bf16x8 pf = *reinterpret_cast<bf16x8*>(&pw);
      oa0 = __builtin_amdgcn_mfma_f32_32x32x16_bf16(vf[0 * 2 + kg], pf, oa0, 0, 0, 0);
      oa1 = __builtin_amdgcn_mfma_f32_32x32x16_bf16(vf[1 * 2 + kg], pf, oa1, 0, 0, 0);
      oaS = __builtin_amdgcn_mfma_f32_32x32x16_bf16(ones, pf, oaS, 0, 0, 0);
    }
    __builtin_amdgcn_s_setprio(0);
  }
  const float inv = 1.0f / oaS[0];  // all regs/halves hold the q-row total
  const int b = bh >> 4, hd = bh & 15;
  _Float16* ob = o + ((size_t)(b * 2048 + qrow)) * 1024 + hd * 64;
#pragma unroll
  for (int r2 = 0; r2 < 16; ++r2) {
    const int d0 = (r2 & 3) + 8 * (r2 >> 2) + 4 * hh;  // 32x32 C layout
    ob[d0] = (_Float16)(oa0[r2] * inv);
    ob[d0 + 32] = (_Float16)(oa1[r2] * inv);
  }
}

// ---------- launch ----------
extern "C" void kernel_launch(void* const* d_in, const int* in_sizes, int n_in,
                              void* d_out, int out_size, void* d_ws, size_t ws_size,
                              hipStream_t stream) {
  const float* x = (const float*)d_in[0];
  const float* w_in = (const float*)d_in[1];
  const float* b_in = (const float*)d_in[2];
  const float* w_norm = (const float*)d_in[3];
  const float* w_out = (const float*)d_in[4];
  const float* b_out = (const float*)d_in[5];
  float* out = (float*)d_out;
  char* ws = (char*)d_ws;
  short* xn = (short*)(ws);                       // 16 MB [8192][1024] bf16
  short* win_b = (short*)(ws + 16777216);         // 6 MB  [3072][1024] bf16
  _Float16* wout_h = (_Float16*)(ws + 23068672);  // 2 MB  [1024][1024] f16
  short* qb = (short*)(ws + 25165824);            // 16 MB [BH][S][64] bf16
  short* kfrag = (short*)(ws + 41943040);         // 16 MB fragment-ordered K
  short* vfrag = (short*)(ws + 58720256);         // 16 MB fragment-ordered V
  _Float16* ob = (_Float16*)(ws + 75497472);      // 16 MB attn out [B][S][1024] f16

  k_cast_bf<<<3072, 256, 0, stream>>>(w_in, win_b, 786432);
  k_cast_f16<<<1024, 256, 0, stream>>>(w_out, wout_h, 262144);
  k_rmsnorm<<<8192, 256, 0, stream>>>(x, w_norm, xn);
  k_gemm_qkv<<<dim3(24, 64), 256, 0, stream>>>(xn, win_b, b_in, qb, kfrag, vfrag);
  k_attn<<<dim3(16, 64), 256, 0, stream>>>(qb, kfrag, vfrag, ob);
  k_gemm_out<<<dim3(8, 64), 256, 0, stream>>>(ob, wout_h, b_out, out);
}

// Round 20
// 212.133 us; speedup vs baseline: 1.3135x; 1.3135x over previous
//
#include <hip/hip_runtime.h>
#include <stdint.h>

typedef short bf16x4 __attribute__((ext_vector_type(4)));
typedef short bf16x8 __attribute__((ext_vector_type(8)));
typedef _Float16 f16x8 __attribute__((ext_vector_type(8)));
typedef float f32x4 __attribute__((ext_vector_type(4)));
typedef float f32x16 __attribute__((ext_vector_type(16)));
typedef unsigned int u32x4 __attribute__((ext_vector_type(4)));
typedef unsigned int u32x2 __attribute__((ext_vector_type(2)));

#if __has_builtin(__builtin_amdgcn_exp2f)
#define EXP2 __builtin_amdgcn_exp2f
#else
#define EXP2 exp2f
#endif

// ---------- helpers ----------
__device__ __forceinline__ short f2bf(float f) {  // RNE f32->bf16 (finite inputs)
  union { float f; uint32_t u; } v; v.f = f;
  uint32_t r = (v.u + 0x7fffu + ((v.u >> 16) & 1u)) >> 16;
  return (short)(uint16_t)r;
}

__device__ __forceinline__ unsigned cvtpk_bf16(float lo, float hi) {
  unsigned r;
  asm("v_cvt_pk_bf16_f32 %0, %1, %2" : "=v"(r) : "v"(lo), "v"(hi));
  return r;
}

// v_permlane32_swap_b32 via the BUILTIN (hazard-safe; round-5 verified).
#if __has_builtin(__builtin_amdgcn_permlane32_swap)
__device__ __forceinline__ void plane32_swap(unsigned& a, unsigned& b) {
  u32x2 r = __builtin_amdgcn_permlane32_swap(a, b, false, false);
  a = r[0]; b = r[1];
}
#else
__device__ __forceinline__ void plane32_swap(unsigned& a, unsigned& b) {
  asm("s_nop 1\n\tv_permlane32_swap_b32 %0, %1" : "+v"(a), "+v"(b));
}
#endif

__device__ __forceinline__ f32x16 zero16() {
  f32x16 z;
#pragma unroll
  for (int i = 0; i < 16; ++i) z[i] = 0.f;
  return z;
}

__device__ __forceinline__ void gld_lds16(const void* g, void* l) {
  __builtin_amdgcn_global_load_lds(
      (__attribute__((address_space(1))) const void*)g,
      (__attribute__((address_space(3))) void*)l, 16, 0, 0);
}

// ---------- RMSNorm + cast to bf16 ----------
__global__ __launch_bounds__(256) void k_rmsnorm(const float* __restrict__ x,
                                                 const float* __restrict__ wn,
                                                 short* __restrict__ xn) {
  const int row = blockIdx.x;      // 8192 rows
  const int t = threadIdx.x;       // 256 threads, 4 floats each
  const float4 v = reinterpret_cast<const float4*>(x + (size_t)row * 1024)[t];
  float ss = v.x * v.x + v.y * v.y + v.z * v.z + v.w * v.w;
#pragma unroll
  for (int m = 32; m >= 1; m >>= 1) ss += __shfl_xor(ss, m, 64);
  __shared__ float red[4];
  if ((t & 63) == 0) red[t >> 6] = ss;
  __syncthreads();
  const float tot = red[0] + red[1] + red[2] + red[3];
  const float rr = rsqrtf(tot * (1.0f / 1024.0f) + 1e-5f);
  const float4 g = reinterpret_cast<const float4*>(wn)[t];
  bf16x4 o;
  o[0] = f2bf(v.x * rr * g.x);
  o[1] = f2bf(v.y * rr * g.y);
  o[2] = f2bf(v.z * rr * g.z);
  o[3] = f2bf(v.w * rr * g.w);
  reinterpret_cast<bf16x4*>(xn + (size_t)row * 1024)[t] = o;
}

// ---------- casts ----------
__global__ __launch_bounds__(256) void k_cast_bf(const float* __restrict__ in,
                                                 short* __restrict__ out, int n4) {
  int i = blockIdx.x * 256 + threadIdx.x;
  if (i >= n4) return;
  float4 v = reinterpret_cast<const float4*>(in)[i];
  bf16x4 o;
  o[0] = f2bf(v.x); o[1] = f2bf(v.y); o[2] = f2bf(v.z); o[3] = f2bf(v.w);
  reinterpret_cast<bf16x4*>(out)[i] = o;
}

__global__ __launch_bounds__(256) void k_cast_f16(const float* __restrict__ in,
                                                  _Float16* __restrict__ out, int n4) {
  int i = blockIdx.x * 256 + threadIdx.x;
  if (i >= n4) return;
  float4 v = reinterpret_cast<const float4*>(in)[i];
  _Float16 o[4] = {(_Float16)v.x, (_Float16)v.y, (_Float16)v.z, (_Float16)v.w};
  reinterpret_cast<ulong1*>(out)[i] = *reinterpret_cast<ulong1*>(o);
}

// ---------- QKV GEMM v4 (round-19 verified): BK=64 + 2-deep dbuf, counted vmcnt ----------
__global__ __launch_bounds__(256) void k_gemm_qkv(const short* __restrict__ A,
                                                  const short* __restrict__ B,
                                                  const float* __restrict__ bias,
                                                  short* __restrict__ qb,
                                                  short* __restrict__ kfrag,
                                                  short* __restrict__ vfrag) {
  __shared__ __align__(16) short As[2][8192];  // 2 x 16KB
  __shared__ __align__(16) short Bs[2][8192];  // 2 x 16KB
  const int t = threadIdx.x;
  // T1: XCD-aware remap (nwg = 24*64 = 1536, 1536%8==0)
  const int orig = blockIdx.y * 24 + blockIdx.x;
  const int swz = (orig & 7) * 192 + (orig >> 3);
  const long bn0 = (long)(swz % 24) * 128;
  const long bm0 = (long)(swz / 24) * 128;
  const int w = t >> 6, l = t & 63;
  const int wr = (w >> 1) * 64, wc = (w & 1) * 64;
  const int lm = l & 15, h = l >> 4;
  f32x4 acc[4][4];
#pragma unroll
  for (int i = 0; i < 4; ++i)
#pragma unroll
    for (int j = 0; j < 4; ++j) acc[i][j] = (f32x4){0.f, 0.f, 0.f, 0.f};
  int ssrc[4], sdst[4];
#pragma unroll
  for (int i = 0; i < 4; ++i) {
    const int idx = i * 256 + t;
    const int row = idx >> 3, gc = idx & 7;
    ssrc[i] = row * 1024 + ((gc ^ (row & 7)) * 8);
    sdst[i] = idx * 8;
  }
  const short* Ag = A + bm0 * 1024;
  const short* Bg = B + bn0 * 1024;
  int aoff[4][2], boff[4][2];
#pragma unroll
  for (int mi = 0; mi < 4; ++mi) {
#pragma unroll
    for (int ks = 0; ks < 2; ++ks) {
      const int ra = wr + mi * 16 + lm;
      aoff[mi][ks] = ra * 64 + (((ks * 4 + h) ^ (ra & 7)) * 8);
      const int rb = wc + mi * 16 + lm;
      boff[mi][ks] = rb * 64 + (((ks * 4 + h) ^ (rb & 7)) * 8);
    }
  }
  auto STAGE = [&](int buf, int kt) {
    const int k0 = kt * 64;
#pragma unroll
    for (int i = 0; i < 4; ++i) gld_lds16(Ag + k0 + ssrc[i], &As[buf][sdst[i]]);
#pragma unroll
    for (int i = 0; i < 4; ++i) gld_lds16(Bg + k0 + ssrc[i], &Bs[buf][sdst[i]]);
  };
  // prologue: tiles 0 (buf0) and 1 (buf1): 16 loads in flight (8 per wave)
  STAGE(0, 0);
  STAGE(1, 1);

  for (int kt = 0; kt < 16; ++kt) {
    // this wave's tile-kt 8 loads retired; kt+1's 8 in flight. Barrier:
    // every wave passed its own vmcnt -> all of tile kt is in LDS.
    asm volatile("s_waitcnt vmcnt(8)" ::: "memory");
    __builtin_amdgcn_s_barrier();
    const int buf = kt & 1;
    // ksub 0
    bf16x8 af[4], bfr[4];
#pragma unroll
    for (int mi = 0; mi < 4; ++mi) af[mi] = *reinterpret_cast<const bf16x8*>(&As[buf][aoff[mi][0]]);
#pragma unroll
    for (int ni = 0; ni < 4; ++ni) bfr[ni] = *reinterpret_cast<const bf16x8*>(&Bs[buf][boff[ni][0]]);
    asm volatile("s_waitcnt lgkmcnt(0)" ::: "memory");
    __builtin_amdgcn_sched_barrier(0);
    __builtin_amdgcn_s_setprio(1);
#pragma unroll
    for (int mi = 0; mi < 4; ++mi)
#pragma unroll
      for (int ni = 0; ni < 4; ++ni)
        acc[mi][ni] = __builtin_amdgcn_mfma_f32_16x16x32_bf16(af[mi], bfr[ni], acc[mi][ni], 0, 0, 0);
    __builtin_amdgcn_s_setprio(0);
    // ksub 1 reads
#pragma unroll
    for (int mi = 0; mi < 4; ++mi) af[mi] = *reinterpret_cast<const bf16x8*>(&As[buf][aoff[mi][1]]);
#pragma unroll
    for (int ni = 0; ni < 4; ++ni) bfr[ni] = *reinterpret_cast<const bf16x8*>(&Bs[buf][boff[ni][1]]);
    asm volatile("s_waitcnt lgkmcnt(0)" ::: "memory");
    __builtin_amdgcn_sched_barrier(0);
    __builtin_amdgcn_s_barrier();  // ALL waves done reading buf -> overwrite ok
    int kn = kt + 2; if (kn > 15) kn = 15;  // tail: junk re-stage, never read
    STAGE(buf, kn);
    __builtin_amdgcn_s_setprio(1);
#pragma unroll
    for (int mi = 0; mi < 4; ++mi)
#pragma unroll
      for (int ni = 0; ni < 4; ++ni)
        acc[mi][ni] = __builtin_amdgcn_mfma_f32_16x16x32_bf16(af[mi], bfr[ni], acc[mi][ni], 0, 0, 0);
    __builtin_amdgcn_s_setprio(0);
  }
#pragma unroll
  for (int ni = 0; ni < 4; ++ni) {
    const int ncol = (int)bn0 + wc + ni * 16 + lm;
    const float bv = bias[ncol];
    const int which = ncol >> 10;
    const int e = ncol & 1023;
    const int hd = e >> 6, d = e & 63;
#pragma unroll
    for (int mi = 0; mi < 4; ++mi) {
#pragma unroll
      for (int r = 0; r < 4; ++r) {
        const long mrow = bm0 + wr + mi * 16 + h * 4 + r;
        const float val = acc[mi][ni][r] + bv;
        const long bh = (mrow >> 11) * 16 + hd;
        const int seq = (int)(mrow & 2047);
        if (which == 0) {
          const long off = (bh * 2048 + seq) * 64 + d;
          qb[off] = f2bf(val * 0.18033688011112042f);  // 0.125*log2(e)
        } else if (which == 1) {
          const long off = ((bh * 64 + (seq >> 5)) * 4 + (d >> 4)) * 512 +
                           ((seq & 31) | (((d >> 3) & 1) << 5)) * 8 + (d & 7);
          kfrag[off] = f2bf(val);
        } else {
          const long off = (((bh * 64 + (seq >> 5)) * 2 + (d >> 5)) * 2 +
                            ((seq >> 4) & 1)) * 512 +
                           ((d & 31) | (((seq >> 3) & 1) << 5)) * 8 + (seq & 7);
          vfrag[off] = f2bf(val);
        }
      }
    }
  }
}

// ---------- out-proj GEMM (fp16 inputs for precision, fp32 out) ----------
__global__ __launch_bounds__(256) void k_gemm_out(const _Float16* __restrict__ A,
                                                  const _Float16* __restrict__ B,
                                                  const float* __restrict__ bias,
                                                  float* __restrict__ outp) {
  __shared__ __align__(16) _Float16 As[128 * 32];
  __shared__ __align__(16) _Float16 Bs[128 * 32];
  const int t = threadIdx.x;
  // T1: nwg = 8*64 = 512, 512%8==0
  const int orig = blockIdx.y * 8 + blockIdx.x;
  const int swz = (orig & 7) * 64 + (orig >> 3);
  const long bn0 = (long)(swz % 8) * 128;
  const long bm0 = (long)(swz / 8) * 128;
  const int w = t >> 6, l = t & 63;
  const int wr = (w >> 1) * 64, wc = (w & 1) * 64;
  const int lm = l & 15, h = l >> 4;
  f32x4 acc[4][4];
#pragma unroll
  for (int i = 0; i < 4; ++i)
#pragma unroll
    for (int j = 0; j < 4; ++j) acc[i][j] = (f32x4){0.f, 0.f, 0.f, 0.f};
  const int srow = t >> 2, scol = (t & 3) * 8;
  const _Float16* Ag = A + (bm0 + srow) * 1024 + scol;
  const _Float16* Bg = B + (bn0 + srow) * 1024 + scol;
  _Float16* AsP = As + t * 8;
  _Float16* BsP = Bs + t * 8;
  for (int kt = 0; kt < 32; ++kt) {
    const int k0 = kt << 5;
    gld_lds16(Ag + k0, AsP);
    gld_lds16(Ag + k0 + 64 * 1024, AsP + 2048);
    gld_lds16(Bg + k0, BsP);
    gld_lds16(Bg + k0 + 64 * 1024, BsP + 2048);
    __syncthreads();
    f16x8 af[4], bfr[4];
#pragma unroll
    for (int mi = 0; mi < 4; ++mi)
      af[mi] = *reinterpret_cast<const f16x8*>(As + (wr + mi * 16 + lm) * 32 + h * 8);
#pragma unroll
    for (int ni = 0; ni < 4; ++ni)
      bfr[ni] = *reinterpret_cast<const f16x8*>(Bs + (wc + ni * 16 + lm) * 32 + h * 8);
    __builtin_amdgcn_s_setprio(1);
#pragma unroll
    for (int mi = 0; mi < 4; ++mi)
#pragma unroll
      for (int ni = 0; ni < 4; ++ni)
        acc[mi][ni] = __builtin_amdgcn_mfma_f32_16x16x32_f16(af[mi], bfr[ni], acc[mi][ni], 0, 0, 0);
    __builtin_amdgcn_s_setprio(0);
    __syncthreads();
  }
#pragma unroll
  for (int ni = 0; ni < 4; ++ni) {
    const int ncol = (int)bn0 + wc + ni * 16 + lm;
    const float bv = bias[ncol];
#pragma unroll
    for (int mi = 0; mi < 4; ++mi) {
#pragma unroll
      for (int r = 0; r < 4; ++r) {
        const long mrow = bm0 + wr + mi * 16 + h * 4 + r;
        outp[mrow * 1024 + ncol] = acc[mi][ni][r] + bv;
      }
    }
  }
}

// ---------- flash attention v14 (round-18 verified, 82.4us): reinstated verbatim ----------
// (round-19's m16c C-seed pushed unified regs past the 128 cap -> loop spills,
// FETCH/WRITE +17MB, 2x slower. Reverted; zero-init + EXP2(s-16) restored.)
__global__ __launch_bounds__(256, 4) void k_attn(const short* __restrict__ q,
                                                 const short* __restrict__ kfrag,
                                                 const short* __restrict__ vfrag,
                                                 _Float16* __restrict__ o) {
  __shared__ __align__(16) short KV[4][4096];  // per tile: K 2048 | V 2048 shorts
  const int orig = blockIdx.y * 16 + blockIdx.x;
  const int work = (orig & 7) * 128 + (orig >> 3);
  const int bh = work >> 4;    // 64 heads
  const int qt = work & 15;    // 16 q-tiles of 128 rows
  const int t = threadIdx.x;
  const int w = t >> 6, l = t & 63;
  const int lq = l & 31, hh = l >> 5;
  const int qrow = qt * 128 + w * 32 + lq;

  bf16x8 qf[4];
  const short* qp = q + ((size_t)(bh * 2048 + qrow)) * 64 + hh * 8;
#pragma unroll
  for (int db = 0; db < 4; ++db)
    qf[db] = *reinterpret_cast<const bf16x8*>(qp + db * 16);

  bf16x8 ones;
#pragma unroll
  for (int i = 0; i < 8; ++i) ones[i] = (short)0x3F80;  // bf16 1.0

  const int goff = (w * 64 + l) * 8;  // shorts (lane-linear, wave-uniform base)
  const short* ksrc = kfrag + (size_t)bh * 64 * 2048 + goff;  // + kt*2048
  const short* vsrc = vfrag + (size_t)bh * 64 * 2048 + goff;

  f32x16 oa0 = zero16(), oa1 = zero16(), oaS = zero16();

#pragma unroll
  for (int p = 0; p < 3; ++p) {
    gld_lds16(ksrc + p * 2048, &KV[p][goff]);
    gld_lds16(vsrc + p * 2048, &KV[p][2048 + goff]);
  }

#pragma unroll 1
  for (int kt = 0; kt < 64; ++kt) {
    asm volatile("s_waitcnt vmcnt(4)" ::: "memory");
    __builtin_amdgcn_s_barrier();
    const short* kb_ = KV[kt & 3];
    bf16x8 kf[4], vf[4];
#pragma unroll
    for (int db = 0; db < 4; ++db)
      kf[db] = *reinterpret_cast<const bf16x8*>(kb_ + db * 512 + l * 8);
#pragma unroll
    for (int i = 0; i < 4; ++i)
      vf[i] = *reinterpret_cast<const bf16x8*>(kb_ + 2048 + i * 512 + l * 8);
    // stage tile kt+3 (its readers finished before barrier(kt); tail clamp)
    int kn = kt + 3; if (kn > 63) kn = 63;
    gld_lds16(ksrc + kn * 2048, &KV[(kt + 3) & 3][goff]);
    gld_lds16(vsrc + kn * 2048, &KV[(kt + 3) & 3][2048 + goff]);

    asm volatile("s_waitcnt lgkmcnt(4)" ::: "memory");  // K frags ready
    __builtin_amdgcn_sched_barrier(0);                  // rule #18 fence
    f32x16 s = zero16();  // 32 keys x 32 q, q-col = lq
    __builtin_amdgcn_s_setprio(1);
#pragma unroll
    for (int db = 0; db < 4; ++db)
      s = __builtin_amdgcn_mfma_f32_32x32x16_bf16(kf[db], qf[db], s, 0, 0, 0);
    __builtin_amdgcn_s_setprio(0);
    asm volatile("s_waitcnt lgkmcnt(0)" ::: "memory");  // V frags ready
    __builtin_amdgcn_sched_barrier(0);
    // shift softmax: p = exp2(s - 16), normalization cancels the constant
#pragma unroll
    for (int r = 0; r < 16; ++r) s[r] = EXP2(s[r] - 16.f);
    __builtin_amdgcn_s_setprio(1);
#pragma unroll
    for (int kg = 0; kg < 2; ++kg) {
      const int b0 = kg * 8;
      unsigned w0 = cvtpk_bf16(s[b0 + 0], s[b0 + 1]);
      unsigned w1 = cvtpk_bf16(s[b0 + 2], s[b0 + 3]);
      unsigned w2 = cvtpk_bf16(s[b0 + 4], s[b0 + 5]);
      unsigned w3 = cvtpk_bf16(s[b0 + 6], s[b0 + 7]);
      plane32_swap(w0, w2);
      plane32_swap(w1, w3);
      u32x4 pw = {w0, w1, w2, w3};
      bf16x8 pf = *reinterpret_cast<bf16x8*>(&pw);
      oa0 = __builtin_amdgcn_mfma_f32_32x32x16_bf16(vf[0 * 2 + kg], pf, oa0, 0, 0, 0);
      oa1 = __builtin_amdgcn_mfma_f32_32x32x16_bf16(vf[1 * 2 + kg], pf, oa1, 0, 0, 0);
      oaS = __builtin_amdgcn_mfma_f32_32x32x16_bf16(ones, pf, oaS, 0, 0, 0);
    }
    __builtin_amdgcn_s_setprio(0);
  }
  const float inv = 1.0f / oaS[0];  // all regs/halves hold the q-row total
  const int b = bh >> 4, hd = bh & 15;
  _Float16* ob = o + ((size_t)(b * 2048 + qrow)) * 1024 + hd * 64;
#pragma unroll
  for (int r2 = 0; r2 < 16; ++r2) {
    const int d0 = (r2 & 3) + 8 * (r2 >> 2) + 4 * hh;  // 32x32 C layout
    ob[d0] = (_Float16)(oa0[r2] * inv);
    ob[d0 + 32] = (_Float16)(oa1[r2] * inv);
  }
}

// ---------- launch ----------
extern "C" void kernel_launch(void* const* d_in, const int* in_sizes, int n_in,
                              void* d_out, int out_size, void* d_ws, size_t ws_size,
                              hipStream_t stream) {
  const float* x = (const float*)d_in[0];
  const float* w_in = (const float*)d_in[1];
  const float* b_in = (const float*)d_in[2];
  const float* w_norm = (const float*)d_in[3];
  const float* w_out = (const float*)d_in[4];
  const float* b_out = (const float*)d_in[5];
  float* out = (float*)d_out;
  char* ws = (char*)d_ws;
  short* xn = (short*)(ws);                       // 16 MB [8192][1024] bf16
  short* win_b = (short*)(ws + 16777216);         // 6 MB  [3072][1024] bf16
  _Float16* wout_h = (_Float16*)(ws + 23068672);  // 2 MB  [1024][1024] f16
  short* qb = (short*)(ws + 25165824);            // 16 MB [BH][S][64] bf16
  short* kfrag = (short*)(ws + 41943040);         // 16 MB fragment-ordered K
  short* vfrag = (short*)(ws + 58720256);         // 16 MB fragment-ordered V
  _Float16* ob = (_Float16*)(ws + 75497472);      // 16 MB attn out [B][S][1024] f16

  k_cast_bf<<<3072, 256, 0, stream>>>(w_in, win_b, 786432);
  k_cast_f16<<<1024, 256, 0, stream>>>(w_out, wout_h, 262144);
  k_rmsnorm<<<8192, 256, 0, stream>>>(x, w_norm, xn);
  k_gemm_qkv<<<dim3(24, 64), 256, 0, stream>>>(xn, win_b, b_in, qb, kfrag, vfrag);
  k_attn<<<dim3(16, 64), 256, 0, stream>>>(qb, kfrag, vfrag, ob);
  k_gemm_out<<<dim3(8, 64), 256, 0, stream>>>(ob, wout_h, b_out, out);
}

// Round 21
// 197.919 us; speedup vs baseline: 1.4078x; 1.0718x over previous
//
#include <hip/hip_runtime.h>
#include <stdint.h>

typedef short bf16x4 __attribute__((ext_vector_type(4)));
typedef short bf16x8 __attribute__((ext_vector_type(8)));
typedef _Float16 f16x8 __attribute__((ext_vector_type(8)));
typedef float f32x4 __attribute__((ext_vector_type(4)));
typedef float f32x16 __attribute__((ext_vector_type(16)));
typedef unsigned int u32x4 __attribute__((ext_vector_type(4)));
typedef unsigned int u32x2 __attribute__((ext_vector_type(2)));

#if __has_builtin(__builtin_amdgcn_exp2f)
#define EXP2 __builtin_amdgcn_exp2f
#else
#define EXP2 exp2f
#endif

// ---------- helpers ----------
__device__ __forceinline__ short f2bf(float f) {  // RNE f32->bf16 (finite inputs)
  union { float f; uint32_t u; } v; v.f = f;
  uint32_t r = (v.u + 0x7fffu + ((v.u >> 16) & 1u)) >> 16;
  return (short)(uint16_t)r;
}

__device__ __forceinline__ unsigned cvtpk_bf16(float lo, float hi) {
  unsigned r;
  asm("v_cvt_pk_bf16_f32 %0, %1, %2" : "=v"(r) : "v"(lo), "v"(hi));
  return r;
}

// v_permlane32_swap_b32 via the BUILTIN (hazard-safe; round-5 verified).
#if __has_builtin(__builtin_amdgcn_permlane32_swap)
__device__ __forceinline__ void plane32_swap(unsigned& a, unsigned& b) {
  u32x2 r = __builtin_amdgcn_permlane32_swap(a, b, false, false);
  a = r[0]; b = r[1];
}
#else
__device__ __forceinline__ void plane32_swap(unsigned& a, unsigned& b) {
  asm("s_nop 1\n\tv_permlane32_swap_b32 %0, %1" : "+v"(a), "+v"(b));
}
#endif

__device__ __forceinline__ f32x16 zero16() {
  f32x16 z;
#pragma unroll
  for (int i = 0; i < 16; ++i) z[i] = 0.f;
  return z;
}

__device__ __forceinline__ void gld_lds16(const void* g, void* l) {
  __builtin_amdgcn_global_load_lds(
      (__attribute__((address_space(1))) const void*)g,
      (__attribute__((address_space(3))) void*)l, 16, 0, 0);
}

// ---------- RMSNorm + cast to bf16 ----------
__global__ __launch_bounds__(256) void k_rmsnorm(const float* __restrict__ x,
                                                 const float* __restrict__ wn,
                                                 short* __restrict__ xn) {
  const int row = blockIdx.x;      // 8192 rows
  const int t = threadIdx.x;       // 256 threads, 4 floats each
  const float4 v = reinterpret_cast<const float4*>(x + (size_t)row * 1024)[t];
  float ss = v.x * v.x + v.y * v.y + v.z * v.z + v.w * v.w;
#pragma unroll
  for (int m = 32; m >= 1; m >>= 1) ss += __shfl_xor(ss, m, 64);
  __shared__ float red[4];
  if ((t & 63) == 0) red[t >> 6] = ss;
  __syncthreads();
  const float tot = red[0] + red[1] + red[2] + red[3];
  const float rr = rsqrtf(tot * (1.0f / 1024.0f) + 1e-5f);
  const float4 g = reinterpret_cast<const float4*>(wn)[t];
  bf16x4 o;
  o[0] = f2bf(v.x * rr * g.x);
  o[1] = f2bf(v.y * rr * g.y);
  o[2] = f2bf(v.z * rr * g.z);
  o[3] = f2bf(v.w * rr * g.w);
  reinterpret_cast<bf16x4*>(xn + (size_t)row * 1024)[t] = o;
}

// ---------- casts ----------
__global__ __launch_bounds__(256) void k_cast_bf(const float* __restrict__ in,
                                                 short* __restrict__ out, int n4) {
  int i = blockIdx.x * 256 + threadIdx.x;
  if (i >= n4) return;
  float4 v = reinterpret_cast<const float4*>(in)[i];
  bf16x4 o;
  o[0] = f2bf(v.x); o[1] = f2bf(v.y); o[2] = f2bf(v.z); o[3] = f2bf(v.w);
  reinterpret_cast<bf16x4*>(out)[i] = o;
}

__global__ __launch_bounds__(256) void k_cast_f16(const float* __restrict__ in,
                                                  _Float16* __restrict__ out, int n4) {
  int i = blockIdx.x * 256 + threadIdx.x;
  if (i >= n4) return;
  float4 v = reinterpret_cast<const float4*>(in)[i];
  _Float16 o[4] = {(_Float16)v.x, (_Float16)v.y, (_Float16)v.z, (_Float16)v.w};
  reinterpret_cast<ulong1*>(out)[i] = *reinterpret_cast<ulong1*>(o);
}

// ---------- QKV GEMM v3 (round-17 verified, ~79us): 128x128, BK=64, XOR swizzle ----------
// (round-20's v4 double-buffer cost occupancy -- 64KB LDS -> 2 blk/CU -- and
// measured 85us > v3's ~79. Reverted to the proven single-buffer BK=64.)
__global__ __launch_bounds__(256) void k_gemm_qkv(const short* __restrict__ A,
                                                  const short* __restrict__ B,
                                                  const float* __restrict__ bias,
                                                  short* __restrict__ qb,
                                                  short* __restrict__ kfrag,
                                                  short* __restrict__ vfrag) {
  __shared__ __align__(16) short As[128 * 64];  // 16KB
  __shared__ __align__(16) short Bs[128 * 64];  // 16KB
  const int t = threadIdx.x;
  // T1: XCD-aware remap (nwg = 24*64 = 1536, 1536%8==0)
  const int orig = blockIdx.y * 24 + blockIdx.x;
  const int swz = (orig & 7) * 192 + (orig >> 3);
  const long bn0 = (long)(swz % 24) * 128;
  const long bm0 = (long)(swz / 24) * 128;
  const int w = t >> 6, l = t & 63;
  const int wr = (w >> 1) * 64, wc = (w & 1) * 64;
  const int lm = l & 15, h = l >> 4;
  f32x4 acc[4][4];
#pragma unroll
  for (int i = 0; i < 4; ++i)
#pragma unroll
    for (int j = 0; j < 4; ++j) acc[i][j] = (f32x4){0.f, 0.f, 0.f, 0.f};
  int ssrc[4], sdst[4];
#pragma unroll
  for (int i = 0; i < 4; ++i) {
    const int idx = i * 256 + t;
    const int row = idx >> 3, gc = idx & 7;
    ssrc[i] = row * 1024 + ((gc ^ (row & 7)) * 8);
    sdst[i] = idx * 8;
  }
  const short* Ag = A + bm0 * 1024;
  const short* Bg = B + bn0 * 1024;
  int aoff[4][2], boff[4][2];
#pragma unroll
  for (int mi = 0; mi < 4; ++mi) {
#pragma unroll
    for (int ks = 0; ks < 2; ++ks) {
      const int ra = wr + mi * 16 + lm;
      aoff[mi][ks] = ra * 64 + (((ks * 4 + h) ^ (ra & 7)) * 8);
      const int rb = wc + mi * 16 + lm;
      boff[mi][ks] = rb * 64 + (((ks * 4 + h) ^ (rb & 7)) * 8);
    }
  }
  for (int kt = 0; kt < 16; ++kt) {
    const int k0 = kt * 64;
#pragma unroll
    for (int i = 0; i < 4; ++i) gld_lds16(Ag + k0 + ssrc[i], As + sdst[i]);
#pragma unroll
    for (int i = 0; i < 4; ++i) gld_lds16(Bg + k0 + ssrc[i], Bs + sdst[i]);
    __syncthreads();
    // ksub 0
    bf16x8 af[4], bfr[4];
#pragma unroll
    for (int mi = 0; mi < 4; ++mi) af[mi] = *reinterpret_cast<const bf16x8*>(As + aoff[mi][0]);
#pragma unroll
    for (int ni = 0; ni < 4; ++ni) bfr[ni] = *reinterpret_cast<const bf16x8*>(Bs + boff[ni][0]);
    __builtin_amdgcn_s_setprio(1);
#pragma unroll
    for (int mi = 0; mi < 4; ++mi)
#pragma unroll
      for (int ni = 0; ni < 4; ++ni)
        acc[mi][ni] = __builtin_amdgcn_mfma_f32_16x16x32_bf16(af[mi], bfr[ni], acc[mi][ni], 0, 0, 0);
    __builtin_amdgcn_s_setprio(0);
    // ksub 1
#pragma unroll
    for (int mi = 0; mi < 4; ++mi) af[mi] = *reinterpret_cast<const bf16x8*>(As + aoff[mi][1]);
#pragma unroll
    for (int ni = 0; ni < 4; ++ni) bfr[ni] = *reinterpret_cast<const bf16x8*>(Bs + boff[ni][1]);
    __builtin_amdgcn_s_setprio(1);
#pragma unroll
    for (int mi = 0; mi < 4; ++mi)
#pragma unroll
      for (int ni = 0; ni < 4; ++ni)
        acc[mi][ni] = __builtin_amdgcn_mfma_f32_16x16x32_bf16(af[mi], bfr[ni], acc[mi][ni], 0, 0, 0);
    __builtin_amdgcn_s_setprio(0);
    __syncthreads();
  }
#pragma unroll
  for (int ni = 0; ni < 4; ++ni) {
    const int ncol = (int)bn0 + wc + ni * 16 + lm;
    const float bv = bias[ncol];
    const int which = ncol >> 10;
    const int e = ncol & 1023;
    const int hd = e >> 6, d = e & 63;
#pragma unroll
    for (int mi = 0; mi < 4; ++mi) {
#pragma unroll
      for (int r = 0; r < 4; ++r) {
        const long mrow = bm0 + wr + mi * 16 + h * 4 + r;
        const float val = acc[mi][ni][r] + bv;
        const long bh = (mrow >> 11) * 16 + hd;
        const int seq = (int)(mrow & 2047);
        if (which == 0) {
          const long off = (bh * 2048 + seq) * 64 + d;
          qb[off] = f2bf(val * 0.18033688011112042f);  // 0.125*log2(e)
        } else if (which == 1) {
          const long off = ((bh * 64 + (seq >> 5)) * 4 + (d >> 4)) * 512 +
                           ((seq & 31) | (((d >> 3) & 1) << 5)) * 8 + (d & 7);
          kfrag[off] = f2bf(val);
        } else {
          const long off = (((bh * 64 + (seq >> 5)) * 2 + (d >> 5)) * 2 +
                            ((seq >> 4) & 1)) * 512 +
                           ((d & 31) | (((seq >> 3) & 1) << 5)) * 8 + (seq & 7);
          vfrag[off] = f2bf(val);
        }
      }
    }
  }
}

// ---------- out-proj GEMM v2: BK=64 + XOR swizzle (round-17-proven transform) ----------
__global__ __launch_bounds__(256) void k_gemm_out(const _Float16* __restrict__ A,
                                                  const _Float16* __restrict__ B,
                                                  const float* __restrict__ bias,
                                                  float* __restrict__ outp) {
  __shared__ __align__(16) _Float16 As[128 * 64];  // 16KB
  __shared__ __align__(16) _Float16 Bs[128 * 64];  // 16KB
  const int t = threadIdx.x;
  // T1: nwg = 8*64 = 512, 512%8==0
  const int orig = blockIdx.y * 8 + blockIdx.x;
  const int swz = (orig & 7) * 64 + (orig >> 3);
  const long bn0 = (long)(swz % 8) * 128;
  const long bm0 = (long)(swz / 8) * 128;
  const int w = t >> 6, l = t & 63;
  const int wr = (w >> 1) * 64, wc = (w & 1) * 64;
  const int lm = l & 15, h = l >> 4;
  f32x4 acc[4][4];
#pragma unroll
  for (int i = 0; i < 4; ++i)
#pragma unroll
    for (int j = 0; j < 4; ++j) acc[i][j] = (f32x4){0.f, 0.f, 0.f, 0.f};
  int ssrc[4], sdst[4];
#pragma unroll
  for (int i = 0; i < 4; ++i) {
    const int idx = i * 256 + t;
    const int row = idx >> 3, gc = idx & 7;
    ssrc[i] = row * 1024 + ((gc ^ (row & 7)) * 8);
    sdst[i] = idx * 8;
  }
  const _Float16* Ag = A + bm0 * 1024;
  const _Float16* Bg = B + bn0 * 1024;
  int aoff[4][2], boff[4][2];
#pragma unroll
  for (int mi = 0; mi < 4; ++mi) {
#pragma unroll
    for (int ks = 0; ks < 2; ++ks) {
      const int ra = wr + mi * 16 + lm;
      aoff[mi][ks] = ra * 64 + (((ks * 4 + h) ^ (ra & 7)) * 8);
      const int rb = wc + mi * 16 + lm;
      boff[mi][ks] = rb * 64 + (((ks * 4 + h) ^ (rb & 7)) * 8);
    }
  }
  for (int kt = 0; kt < 16; ++kt) {
    const int k0 = kt * 64;
#pragma unroll
    for (int i = 0; i < 4; ++i) gld_lds16(Ag + k0 + ssrc[i], As + sdst[i]);
#pragma unroll
    for (int i = 0; i < 4; ++i) gld_lds16(Bg + k0 + ssrc[i], Bs + sdst[i]);
    __syncthreads();
    // ksub 0
    f16x8 af[4], bfr[4];
#pragma unroll
    for (int mi = 0; mi < 4; ++mi) af[mi] = *reinterpret_cast<const f16x8*>(As + aoff[mi][0]);
#pragma unroll
    for (int ni = 0; ni < 4; ++ni) bfr[ni] = *reinterpret_cast<const f16x8*>(Bs + boff[ni][0]);
    __builtin_amdgcn_s_setprio(1);
#pragma unroll
    for (int mi = 0; mi < 4; ++mi)
#pragma unroll
      for (int ni = 0; ni < 4; ++ni)
        acc[mi][ni] = __builtin_amdgcn_mfma_f32_16x16x32_f16(af[mi], bfr[ni], acc[mi][ni], 0, 0, 0);
    __builtin_amdgcn_s_setprio(0);
    // ksub 1
#pragma unroll
    for (int mi = 0; mi < 4; ++mi) af[mi] = *reinterpret_cast<const f16x8*>(As + aoff[mi][1]);
#pragma unroll
    for (int ni = 0; ni < 4; ++ni) bfr[ni] = *reinterpret_cast<const f16x8*>(Bs + boff[ni][1]);
    __builtin_amdgcn_s_setprio(1);
#pragma unroll
    for (int mi = 0; mi < 4; ++mi)
#pragma unroll
      for (int ni = 0; ni < 4; ++ni)
        acc[mi][ni] = __builtin_amdgcn_mfma_f32_16x16x32_f16(af[mi], bfr[ni], acc[mi][ni], 0, 0, 0);
    __builtin_amdgcn_s_setprio(0);
    __syncthreads();
  }
#pragma unroll
  for (int ni = 0; ni < 4; ++ni) {
    const int ncol = (int)bn0 + wc + ni * 16 + lm;
    const float bv = bias[ncol];
#pragma unroll
    for (int mi = 0; mi < 4; ++mi) {
#pragma unroll
      for (int r = 0; r < 4; ++r) {
        const long mrow = bm0 + wr + mi * 16 + h * 4 + r;
        outp[mrow * 1024 + ncol] = acc[mi][ni][r] + bv;
      }
    }
  }
}

// ---------- flash attention v14 (round-18/20 verified, ~82us) ----------
__global__ __launch_bounds__(256, 4) void k_attn(const short* __restrict__ q,
                                                 const short* __restrict__ kfrag,
                                                 const short* __restrict__ vfrag,
                                                 _Float16* __restrict__ o) {
  __shared__ __align__(16) short KV[4][4096];  // per tile: K 2048 | V 2048 shorts
  const int orig = blockIdx.y * 16 + blockIdx.x;
  const int work = (orig & 7) * 128 + (orig >> 3);
  const int bh = work >> 4;    // 64 heads
  const int qt = work & 15;    // 16 q-tiles of 128 rows
  const int t = threadIdx.x;
  const int w = t >> 6, l = t & 63;
  const int lq = l & 31, hh = l >> 5;
  const int qrow = qt * 128 + w * 32 + lq;

  bf16x8 qf[4];
  const short* qp = q + ((size_t)(bh * 2048 + qrow)) * 64 + hh * 8;
#pragma unroll
  for (int db = 0; db < 4; ++db)
    qf[db] = *reinterpret_cast<const bf16x8*>(qp + db * 16);

  bf16x8 ones;
#pragma unroll
  for (int i = 0; i < 8; ++i) ones[i] = (short)0x3F80;  // bf16 1.0

  const int goff = (w * 64 + l) * 8;  // shorts (lane-linear, wave-uniform base)
  const short* ksrc = kfrag + (size_t)bh * 64 * 2048 + goff;  // + kt*2048
  const short* vsrc = vfrag + (size_t)bh * 64 * 2048 + goff;

  f32x16 oa0 = zero16(), oa1 = zero16(), oaS = zero16();

#pragma unroll
  for (int p = 0; p < 3; ++p) {
    gld_lds16(ksrc + p * 2048, &KV[p][goff]);
    gld_lds16(vsrc + p * 2048, &KV[p][2048 + goff]);
  }

#pragma unroll 1
  for (int kt = 0; kt < 64; ++kt) {
    asm volatile("s_waitcnt vmcnt(4)" ::: "memory");
    __builtin_amdgcn_s_barrier();
    const short* kb_ = KV[kt & 3];
    bf16x8 kf[4], vf[4];
#pragma unroll
    for (int db = 0; db < 4; ++db)
      kf[db] = *reinterpret_cast<const bf16x8*>(kb_ + db * 512 + l * 8);
#pragma unroll
    for (int i = 0; i < 4; ++i)
      vf[i] = *reinterpret_cast<const bf16x8*>(kb_ + 2048 + i * 512 + l * 8);
    // stage tile kt+3 (its readers finished before barrier(kt); tail clamp)
    int kn = kt + 3; if (kn > 63) kn = 63;
    gld_lds16(ksrc + kn * 2048, &KV[(kt + 3) & 3][goff]);
    gld_lds16(vsrc + kn * 2048, &KV[(kt + 3) & 3][2048 + goff]);

    asm volatile("s_waitcnt lgkmcnt(4)" ::: "memory");  // K frags ready
    __builtin_amdgcn_sched_barrier(0);                  // rule #18 fence
    f32x16 s = zero16();  // 32 keys x 32 q, q-col = lq
    __builtin_amdgcn_s_setprio(1);
#pragma unroll
    for (int db = 0; db < 4; ++db)
      s = __builtin_amdgcn_mfma_f32_32x32x16_bf16(kf[db], qf[db], s, 0, 0, 0);
    __builtin_amdgcn_s_setprio(0);
    asm volatile("s_waitcnt lgkmcnt(0)" ::: "memory");  // V frags ready
    __builtin_amdgcn_sched_barrier(0);
    // shift softmax: p = exp2(s - 16), normalization cancels the constant
#pragma unroll
    for (int r = 0; r < 16; ++r) s[r] = EXP2(s[r] - 16.f);
    __builtin_amdgcn_s_setprio(1);
#pragma unroll
    for (int kg = 0; kg < 2; ++kg) {
      const int b0 = kg * 8;
      unsigned w0 = cvtpk_bf16(s[b0 + 0], s[b0 + 1]);
      unsigned w1 = cvtpk_bf16(s[b0 + 2], s[b0 + 3]);
      unsigned w2 = cvtpk_bf16(s[b0 + 4], s[b0 + 5]);
      unsigned w3 = cvtpk_bf16(s[b0 + 6], s[b0 + 7]);
      plane32_swap(w0, w2);
      plane32_swap(w1, w3);
      u32x4 pw = {w0, w1, w2, w3};
      bf16x8 pf = *reinterpret_cast<bf16x8*>(&pw);
      oa0 = __builtin_amdgcn_mfma_f32_32x32x16_bf16(vf[0 * 2 + kg], pf, oa0, 0, 0, 0);
      oa1 = __builtin_amdgcn_mfma_f32_32x32x16_bf16(vf[1 * 2 + kg], pf, oa1, 0, 0, 0);
      oaS = __builtin_amdgcn_mfma_f32_32x32x16_bf16(ones, pf, oaS, 0, 0, 0);
    }
    __builtin_amdgcn_s_setprio(0);
  }
  const float inv = 1.0f / oaS[0];  // all regs/halves hold the q-row total
  const int b = bh >> 4, hd = bh & 15;
  _Float16* ob = o + ((size_t)(b * 2048 + qrow)) * 1024 + hd * 64;
#pragma unroll
  for (int r2 = 0; r2 < 16; ++r2) {
    const int d0 = (r2 & 3) + 8 * (r2 >> 2) + 4 * hh;  // 32x32 C layout
    ob[d0] = (_Float16)(oa0[r2] * inv);
    ob[d0 + 32] = (_Float16)(oa1[r2] * inv);
  }
}

// ---------- launch ----------
extern "C" void kernel_launch(void* const* d_in, const int* in_sizes, int n_in,
                              void* d_out, int out_size, void* d_ws, size_t ws_size,
                              hipStream_t stream) {
  const float* x = (const float*)d_in[0];
  const float* w_in = (const float*)d_in[1];
  const float* b_in = (const float*)d_in[2];
  const float* w_norm = (const float*)d_in[3];
  const float* w_out = (const float*)d_in[4];
  const float* b_out = (const float*)d_in[5];
  float* out = (float*)d_out;
  char* ws = (char*)d_ws;
  short* xn = (short*)(ws);                       // 16 MB [8192][1024] bf16
  short* win_b = (short*)(ws + 16777216);         // 6 MB  [3072][1024] bf16
  _Float16* wout_h = (_Float16*)(ws + 23068672);  // 2 MB  [1024][1024] f16
  short* qb = (short*)(ws + 25165824);            // 16 MB [BH][S][64] bf16
  short* kfrag = (short*)(ws + 41943040);         // 16 MB fragment-ordered K
  short* vfrag = (short*)(ws + 58720256);         // 16 MB fragment-ordered V
  _Float16* ob = (_Float16*)(ws + 75497472);      // 16 MB attn out [B][S][1024] f16

  k_cast_bf<<<3072, 256, 0, stream>>>(w_in, win_b, 786432);
  k_cast_f16<<<1024, 256, 0, stream>>>(w_out, wout_h, 262144);
  k_rmsnorm<<<8192, 256, 0, stream>>>(x, w_norm, xn);
  k_gemm_qkv<<<dim3(24, 64), 256, 0, stream>>>(xn, win_b, b_in, qb, kfrag, vfrag);
  k_attn<<<dim3(16, 64), 256, 0, stream>>>(qb, kfrag, vfrag, ob);
  k_gemm_out<<<dim3(8, 64), 256, 0, stream>>>(ob, wout_h, b_out, out);
}

// Round 22
// 194.868 us; speedup vs baseline: 1.4299x; 1.0157x over previous
//
#include <hip/hip_runtime.h>
#include <stdint.h>

typedef short bf16x4 __attribute__((ext_vector_type(4)));
typedef short bf16x8 __attribute__((ext_vector_type(8)));
typedef _Float16 f16x8 __attribute__((ext_vector_type(8)));
typedef float f32x4 __attribute__((ext_vector_type(4)));
typedef float f32x16 __attribute__((ext_vector_type(16)));
typedef unsigned int u32x4 __attribute__((ext_vector_type(4)));
typedef unsigned int u32x2 __attribute__((ext_vector_type(2)));

#if __has_builtin(__builtin_amdgcn_exp2f)
#define EXP2 __builtin_amdgcn_exp2f
#else
#define EXP2 exp2f
#endif

// ---------- helpers ----------
__device__ __forceinline__ short f2bf(float f) {  // RNE f32->bf16 (finite inputs)
  union { float f; uint32_t u; } v; v.f = f;
  uint32_t r = (v.u + 0x7fffu + ((v.u >> 16) & 1u)) >> 16;
  return (short)(uint16_t)r;
}

__device__ __forceinline__ unsigned cvtpk_bf16(float lo, float hi) {
  unsigned r;
  asm("v_cvt_pk_bf16_f32 %0, %1, %2" : "=v"(r) : "v"(lo), "v"(hi));
  return r;
}

// v_permlane32_swap_b32 via the BUILTIN (hazard-safe; round-5 verified).
#if __has_builtin(__builtin_amdgcn_permlane32_swap)
__device__ __forceinline__ void plane32_swap(unsigned& a, unsigned& b) {
  u32x2 r = __builtin_amdgcn_permlane32_swap(a, b, false, false);
  a = r[0]; b = r[1];
}
#else
__device__ __forceinline__ void plane32_swap(unsigned& a, unsigned& b) {
  asm("s_nop 1\n\tv_permlane32_swap_b32 %0, %1" : "+v"(a), "+v"(b));
}
#endif

__device__ __forceinline__ f32x16 zero16() {
  f32x16 z;
#pragma unroll
  for (int i = 0; i < 16; ++i) z[i] = 0.f;
  return z;
}

__device__ __forceinline__ void gld_lds16(const void* g, void* l) {
  __builtin_amdgcn_global_load_lds(
      (__attribute__((address_space(1))) const void*)g,
      (__attribute__((address_space(3))) void*)l, 16, 0, 0);
}

// ---------- RMSNorm + cast to bf16 ----------
__global__ __launch_bounds__(256) void k_rmsnorm(const float* __restrict__ x,
                                                 const float* __restrict__ wn,
                                                 short* __restrict__ xn) {
  const int row = blockIdx.x;      // 8192 rows
  const int t = threadIdx.x;       // 256 threads, 4 floats each
  const float4 v = reinterpret_cast<const float4*>(x + (size_t)row * 1024)[t];
  float ss = v.x * v.x + v.y * v.y + v.z * v.z + v.w * v.w;
#pragma unroll
  for (int m = 32; m >= 1; m >>= 1) ss += __shfl_xor(ss, m, 64);
  __shared__ float red[4];
  if ((t & 63) == 0) red[t >> 6] = ss;
  __syncthreads();
  const float tot = red[0] + red[1] + red[2] + red[3];
  const float rr = rsqrtf(tot * (1.0f / 1024.0f) + 1e-5f);
  const float4 g = reinterpret_cast<const float4*>(wn)[t];
  bf16x4 o;
  o[0] = f2bf(v.x * rr * g.x);
  o[1] = f2bf(v.y * rr * g.y);
  o[2] = f2bf(v.z * rr * g.z);
  o[3] = f2bf(v.w * rr * g.w);
  reinterpret_cast<bf16x4*>(xn + (size_t)row * 1024)[t] = o;
}

// ---------- casts ----------
__global__ __launch_bounds__(256) void k_cast_bf(const float* __restrict__ in,
                                                 short* __restrict__ out, int n4) {
  int i = blockIdx.x * 256 + threadIdx.x;
  if (i >= n4) return;
  float4 v = reinterpret_cast<const float4*>(in)[i];
  bf16x4 o;
  o[0] = f2bf(v.x); o[1] = f2bf(v.y); o[2] = f2bf(v.z); o[3] = f2bf(v.w);
  reinterpret_cast<bf16x4*>(out)[i] = o;
}

__global__ __launch_bounds__(256) void k_cast_f16(const float* __restrict__ in,
                                                  _Float16* __restrict__ out, int n4) {
  int i = blockIdx.x * 256 + threadIdx.x;
  if (i >= n4) return;
  float4 v = reinterpret_cast<const float4*>(in)[i];
  _Float16 o[4] = {(_Float16)v.x, (_Float16)v.y, (_Float16)v.z, (_Float16)v.w};
  reinterpret_cast<ulong1*>(out)[i] = *reinterpret_cast<ulong1*>(o);
}

// ---------- QKV GEMM v3 (round-17/21 verified, ~79us): 128x128, BK=64, XOR swizzle ----------
__global__ __launch_bounds__(256) void k_gemm_qkv(const short* __restrict__ A,
                                                  const short* __restrict__ B,
                                                  const float* __restrict__ bias,
                                                  short* __restrict__ qb,
                                                  short* __restrict__ kfrag,
                                                  short* __restrict__ vfrag) {
  __shared__ __align__(16) short As[128 * 64];  // 16KB
  __shared__ __align__(16) short Bs[128 * 64];  // 16KB
  const int t = threadIdx.x;
  // T1: XCD-aware remap (nwg = 24*64 = 1536, 1536%8==0)
  const int orig = blockIdx.y * 24 + blockIdx.x;
  const int swz = (orig & 7) * 192 + (orig >> 3);
  const long bn0 = (long)(swz % 24) * 128;
  const long bm0 = (long)(swz / 24) * 128;
  const int w = t >> 6, l = t & 63;
  const int wr = (w >> 1) * 64, wc = (w & 1) * 64;
  const int lm = l & 15, h = l >> 4;
  f32x4 acc[4][4];
#pragma unroll
  for (int i = 0; i < 4; ++i)
#pragma unroll
    for (int j = 0; j < 4; ++j) acc[i][j] = (f32x4){0.f, 0.f, 0.f, 0.f};
  int ssrc[4], sdst[4];
#pragma unroll
  for (int i = 0; i < 4; ++i) {
    const int idx = i * 256 + t;
    const int row = idx >> 3, gc = idx & 7;
    ssrc[i] = row * 1024 + ((gc ^ (row & 7)) * 8);
    sdst[i] = idx * 8;
  }
  const short* Ag = A + bm0 * 1024;
  const short* Bg = B + bn0 * 1024;
  int aoff[4][2], boff[4][2];
#pragma unroll
  for (int mi = 0; mi < 4; ++mi) {
#pragma unroll
    for (int ks = 0; ks < 2; ++ks) {
      const int ra = wr + mi * 16 + lm;
      aoff[mi][ks] = ra * 64 + (((ks * 4 + h) ^ (ra & 7)) * 8);
      const int rb = wc + mi * 16 + lm;
      boff[mi][ks] = rb * 64 + (((ks * 4 + h) ^ (rb & 7)) * 8);
    }
  }
  for (int kt = 0; kt < 16; ++kt) {
    const int k0 = kt * 64;
#pragma unroll
    for (int i = 0; i < 4; ++i) gld_lds16(Ag + k0 + ssrc[i], As + sdst[i]);
#pragma unroll
    for (int i = 0; i < 4; ++i) gld_lds16(Bg + k0 + ssrc[i], Bs + sdst[i]);
    __syncthreads();
    // ksub 0
    bf16x8 af[4], bfr[4];
#pragma unroll
    for (int mi = 0; mi < 4; ++mi) af[mi] = *reinterpret_cast<const bf16x8*>(As + aoff[mi][0]);
#pragma unroll
    for (int ni = 0; ni < 4; ++ni) bfr[ni] = *reinterpret_cast<const bf16x8*>(Bs + boff[ni][0]);
    __builtin_amdgcn_s_setprio(1);
#pragma unroll
    for (int mi = 0; mi < 4; ++mi)
#pragma unroll
      for (int ni = 0; ni < 4; ++ni)
        acc[mi][ni] = __builtin_amdgcn_mfma_f32_16x16x32_bf16(af[mi], bfr[ni], acc[mi][ni], 0, 0, 0);
    __builtin_amdgcn_s_setprio(0);
    // ksub 1
#pragma unroll
    for (int mi = 0; mi < 4; ++mi) af[mi] = *reinterpret_cast<const bf16x8*>(As + aoff[mi][1]);
#pragma unroll
    for (int ni = 0; ni < 4; ++ni) bfr[ni] = *reinterpret_cast<const bf16x8*>(Bs + boff[ni][1]);
    __builtin_amdgcn_s_setprio(1);
#pragma unroll
    for (int mi = 0; mi < 4; ++mi)
#pragma unroll
      for (int ni = 0; ni < 4; ++ni)
        acc[mi][ni] = __builtin_amdgcn_mfma_f32_16x16x32_bf16(af[mi], bfr[ni], acc[mi][ni], 0, 0, 0);
    __builtin_amdgcn_s_setprio(0);
    __syncthreads();
  }
#pragma unroll
  for (int ni = 0; ni < 4; ++ni) {
    const int ncol = (int)bn0 + wc + ni * 16 + lm;
    const float bv = bias[ncol];
    const int which = ncol >> 10;
    const int e = ncol & 1023;
    const int hd = e >> 6, d = e & 63;
#pragma unroll
    for (int mi = 0; mi < 4; ++mi) {
#pragma unroll
      for (int r = 0; r < 4; ++r) {
        const long mrow = bm0 + wr + mi * 16 + h * 4 + r;
        const float val = acc[mi][ni][r] + bv;
        const long bh = (mrow >> 11) * 16 + hd;
        const int seq = (int)(mrow & 2047);
        if (which == 0) {
          const long off = (bh * 2048 + seq) * 64 + d;
          qb[off] = f2bf(val * 0.18033688011112042f);  // 0.125*log2(e)
        } else if (which == 1) {
          const long off = ((bh * 64 + (seq >> 5)) * 4 + (d >> 4)) * 512 +
                           ((seq & 31) | (((d >> 3) & 1) << 5)) * 8 + (d & 7);
          kfrag[off] = f2bf(val);
        } else {
          const long off = (((bh * 64 + (seq >> 5)) * 2 + (d >> 5)) * 2 +
                            ((seq >> 4) & 1)) * 512 +
                           ((d & 31) | (((seq >> 3) & 1) << 5)) * 8 + (seq & 7);
          vfrag[off] = f2bf(val);
        }
      }
    }
  }
}

// ---------- out-proj GEMM v2 (round-21 verified): BK=64 + XOR swizzle ----------
__global__ __launch_bounds__(256) void k_gemm_out(const _Float16* __restrict__ A,
                                                  const _Float16* __restrict__ B,
                                                  const float* __restrict__ bias,
                                                  float* __restrict__ outp) {
  __shared__ __align__(16) _Float16 As[128 * 64];  // 16KB
  __shared__ __align__(16) _Float16 Bs[128 * 64];  // 16KB
  const int t = threadIdx.x;
  // T1: nwg = 8*64 = 512, 512%8==0
  const int orig = blockIdx.y * 8 + blockIdx.x;
  const int swz = (orig & 7) * 64 + (orig >> 3);
  const long bn0 = (long)(swz % 8) * 128;
  const long bm0 = (long)(swz / 8) * 128;
  const int w = t >> 6, l = t & 63;
  const int wr = (w >> 1) * 64, wc = (w & 1) * 64;
  const int lm = l & 15, h = l >> 4;
  f32x4 acc[4][4];
#pragma unroll
  for (int i = 0; i < 4; ++i)
#pragma unroll
    for (int j = 0; j < 4; ++j) acc[i][j] = (f32x4){0.f, 0.f, 0.f, 0.f};
  int ssrc[4], sdst[4];
#pragma unroll
  for (int i = 0; i < 4; ++i) {
    const int idx = i * 256 + t;
    const int row = idx >> 3, gc = idx & 7;
    ssrc[i] = row * 1024 + ((gc ^ (row & 7)) * 8);
    sdst[i] = idx * 8;
  }
  const _Float16* Ag = A + bm0 * 1024;
  const _Float16* Bg = B + bn0 * 1024;
  int aoff[4][2], boff[4][2];
#pragma unroll
  for (int mi = 0; mi < 4; ++mi) {
#pragma unroll
    for (int ks = 0; ks < 2; ++ks) {
      const int ra = wr + mi * 16 + lm;
      aoff[mi][ks] = ra * 64 + (((ks * 4 + h) ^ (ra & 7)) * 8);
      const int rb = wc + mi * 16 + lm;
      boff[mi][ks] = rb * 64 + (((ks * 4 + h) ^ (rb & 7)) * 8);
    }
  }
  for (int kt = 0; kt < 16; ++kt) {
    const int k0 = kt * 64;
#pragma unroll
    for (int i = 0; i < 4; ++i) gld_lds16(Ag + k0 + ssrc[i], As + sdst[i]);
#pragma unroll
    for (int i = 0; i < 4; ++i) gld_lds16(Bg + k0 + ssrc[i], Bs + sdst[i]);
    __syncthreads();
    // ksub 0
    f16x8 af[4], bfr[4];
#pragma unroll
    for (int mi = 0; mi < 4; ++mi) af[mi] = *reinterpret_cast<const f16x8*>(As + aoff[mi][0]);
#pragma unroll
    for (int ni = 0; ni < 4; ++ni) bfr[ni] = *reinterpret_cast<const f16x8*>(Bs + boff[ni][0]);
    __builtin_amdgcn_s_setprio(1);
#pragma unroll
    for (int mi = 0; mi < 4; ++mi)
#pragma unroll
      for (int ni = 0; ni < 4; ++ni)
        acc[mi][ni] = __builtin_amdgcn_mfma_f32_16x16x32_f16(af[mi], bfr[ni], acc[mi][ni], 0, 0, 0);
    __builtin_amdgcn_s_setprio(0);
    // ksub 1
#pragma unroll
    for (int mi = 0; mi < 4; ++mi) af[mi] = *reinterpret_cast<const f16x8*>(As + aoff[mi][1]);
#pragma unroll
    for (int ni = 0; ni < 4; ++ni) bfr[ni] = *reinterpret_cast<const f16x8*>(Bs + boff[ni][1]);
    __builtin_amdgcn_s_setprio(1);
#pragma unroll
    for (int mi = 0; mi < 4; ++mi)
#pragma unroll
      for (int ni = 0; ni < 4; ++ni)
        acc[mi][ni] = __builtin_amdgcn_mfma_f32_16x16x32_f16(af[mi], bfr[ni], acc[mi][ni], 0, 0, 0);
    __builtin_amdgcn_s_setprio(0);
    __syncthreads();
  }
#pragma unroll
  for (int ni = 0; ni < 4; ++ni) {
    const int ncol = (int)bn0 + wc + ni * 16 + lm;
    const float bv = bias[ncol];
#pragma unroll
    for (int mi = 0; mi < 4; ++mi) {
#pragma unroll
      for (int r = 0; r < 4; ++r) {
        const long mrow = bm0 + wr + mi * 16 + h * 4 + r;
        outp[mrow * 1024 + ncol] = acc[mi][ni][r] + bv;
      }
    }
  }
}

// ---------- flash attention v16: v14 minus the -16 shift (p = exp2(s) raw) ----------
// Softmax is shift-invariant and fp is scale-invariant; without the shift
// p <= ~2^20 and row sums <= ~2^31 -- far inside f32/bf16 exponent range
// (overflow needs s > 127, unreachable). Deletes 16 v_sub/iter from the
// ~48%-busy VALU pipe. No new persistent registers (round-19 trap avoided).
__global__ __launch_bounds__(256, 4) void k_attn(const short* __restrict__ q,
                                                 const short* __restrict__ kfrag,
                                                 const short* __restrict__ vfrag,
                                                 _Float16* __restrict__ o) {
  __shared__ __align__(16) short KV[4][4096];  // per tile: K 2048 | V 2048 shorts
  const int orig = blockIdx.y * 16 + blockIdx.x;
  const int work = (orig & 7) * 128 + (orig >> 3);
  const int bh = work >> 4;    // 64 heads
  const int qt = work & 15;    // 16 q-tiles of 128 rows
  const int t = threadIdx.x;
  const int w = t >> 6, l = t & 63;
  const int lq = l & 31, hh = l >> 5;
  const int qrow = qt * 128 + w * 32 + lq;

  bf16x8 qf[4];
  const short* qp = q + ((size_t)(bh * 2048 + qrow)) * 64 + hh * 8;
#pragma unroll
  for (int db = 0; db < 4; ++db)
    qf[db] = *reinterpret_cast<const bf16x8*>(qp + db * 16);

  bf16x8 ones;
#pragma unroll
  for (int i = 0; i < 8; ++i) ones[i] = (short)0x3F80;  // bf16 1.0

  const int goff = (w * 64 + l) * 8;  // shorts (lane-linear, wave-uniform base)
  const short* ksrc = kfrag + (size_t)bh * 64 * 2048 + goff;  // + kt*2048
  const short* vsrc = vfrag + (size_t)bh * 64 * 2048 + goff;

  f32x16 oa0 = zero16(), oa1 = zero16(), oaS = zero16();

#pragma unroll
  for (int p = 0; p < 3; ++p) {
    gld_lds16(ksrc + p * 2048, &KV[p][goff]);
    gld_lds16(vsrc + p * 2048, &KV[p][2048 + goff]);
  }

#pragma unroll 1
  for (int kt = 0; kt < 64; ++kt) {
    asm volatile("s_waitcnt vmcnt(4)" ::: "memory");
    __builtin_amdgcn_s_barrier();
    const short* kb_ = KV[kt & 3];
    bf16x8 kf[4], vf[4];
#pragma unroll
    for (int db = 0; db < 4; ++db)
      kf[db] = *reinterpret_cast<const bf16x8*>(kb_ + db * 512 + l * 8);
#pragma unroll
    for (int i = 0; i < 4; ++i)
      vf[i] = *reinterpret_cast<const bf16x8*>(kb_ + 2048 + i * 512 + l * 8);
    // stage tile kt+3 (its readers finished before barrier(kt); tail clamp)
    int kn = kt + 3; if (kn > 63) kn = 63;
    gld_lds16(ksrc + kn * 2048, &KV[(kt + 3) & 3][goff]);
    gld_lds16(vsrc + kn * 2048, &KV[(kt + 3) & 3][2048 + goff]);

    asm volatile("s_waitcnt lgkmcnt(4)" ::: "memory");  // K frags ready
    __builtin_amdgcn_sched_barrier(0);                  // rule #18 fence
    f32x16 s = zero16();  // 32 keys x 32 q, q-col = lq
    __builtin_amdgcn_s_setprio(1);
#pragma unroll
    for (int db = 0; db < 4; ++db)
      s = __builtin_amdgcn_mfma_f32_32x32x16_bf16(kf[db], qf[db], s, 0, 0, 0);
    __builtin_amdgcn_s_setprio(0);
    asm volatile("s_waitcnt lgkmcnt(0)" ::: "memory");  // V frags ready
    __builtin_amdgcn_sched_barrier(0);
    // raw exp2 softmax (shift-free; normalization absorbs the scale)
#pragma unroll
    for (int r = 0; r < 16; ++r) s[r] = EXP2(s[r]);
    __builtin_amdgcn_s_setprio(1);
#pragma unroll
    for (int kg = 0; kg < 2; ++kg) {
      const int b0 = kg * 8;
      unsigned w0 = cvtpk_bf16(s[b0 + 0], s[b0 + 1]);
      unsigned w1 = cvtpk_bf16(s[b0 + 2], s[b0 + 3]);
      unsigned w2 = cvtpk_bf16(s[b0 + 4], s[b0 + 5]);
      unsigned w3 = cvtpk_bf16(s[b0 + 6], s[b0 + 7]);
      plane32_swap(w0, w2);
      plane32_swap(w1, w3);
      u32x4 pw = {w0, w1, w2, w3};
      bf16x8 pf = *reinterpret_cast<bf16x8*>(&pw);
      oa0 = __builtin_amdgcn_mfma_f32_32x32x16_bf16(vf[0 * 2 + kg], pf, oa0, 0, 0, 0);
      oa1 = __builtin_amdgcn_mfma_f32_32x32x16_bf16(vf[1 * 2 + kg], pf, oa1, 0, 0, 0);
      oaS = __builtin_amdgcn_mfma_f32_32x32x16_bf16(ones, pf, oaS, 0, 0, 0);
    }
    __builtin_amdgcn_s_setprio(0);
  }
  const float inv = 1.0f / oaS[0];  // all regs/halves hold the q-row total
  const int b = bh >> 4, hd = bh & 15;
  _Float16* ob = o + ((size_t)(b * 2048 + qrow)) * 1024 + hd * 64;
#pragma unroll
  for (int r2 = 0; r2 < 16; ++r2) {
    const int d0 = (r2 & 3) + 8 * (r2 >> 2) + 4 * hh;  // 32x32 C layout
    ob[d0] = (_Float16)(oa0[r2] * inv);
    ob[d0 + 32] = (_Float16)(oa1[r2] * inv);
  }
}

// ---------- launch ----------
extern "C" void kernel_launch(void* const* d_in, const int* in_sizes, int n_in,
                              void* d_out, int out_size, void* d_ws, size_t ws_size,
                              hipStream_t stream) {
  const float* x = (const float*)d_in[0];
  const float* w_in = (const float*)d_in[1];
  const float* b_in = (const float*)d_in[2];
  const float* w_norm = (const float*)d_in[3];
  const float* w_out = (const float*)d_in[4];
  const float* b_out = (const float*)d_in[5];
  float* out = (float*)d_out;
  char* ws = (char*)d_ws;
  short* xn = (short*)(ws);                       // 16 MB [8192][1024] bf16
  short* win_b = (short*)(ws + 16777216);         // 6 MB  [3072][1024] bf16
  _Float16* wout_h = (_Float16*)(ws + 23068672);  // 2 MB  [1024][1024] f16
  short* qb = (short*)(ws + 25165824);            // 16 MB [BH][S][64] bf16
  short* kfrag = (short*)(ws + 41943040);         // 16 MB fragment-ordered K
  short* vfrag = (short*)(ws + 58720256);         // 16 MB fragment-ordered V
  _Float16* ob = (_Float16*)(ws + 75497472);      // 16 MB attn out [B][S][1024] f16

  k_cast_bf<<<3072, 256, 0, stream>>>(w_in, win_b, 786432);
  k_cast_f16<<<1024, 256, 0, stream>>>(w_out, wout_h, 262144);
  k_rmsnorm<<<8192, 256, 0, stream>>>(x, w_norm, xn);
  k_gemm_qkv<<<dim3(24, 64), 256, 0, stream>>>(xn, win_b, b_in, qb, kfrag, vfrag);
  k_attn<<<dim3(16, 64), 256, 0, stream>>>(qb, kfrag, vfrag, ob);
  k_gemm_out<<<dim3(8, 64), 256, 0, stream>>>(ob, wout_h, b_out, out);
}